// Round 2
// baseline (334.798 us; speedup 1.0000x reference)
//
#include <hip/hip_runtime.h>
#include <hip/hip_bf16.h>

// C2QAttention: softmax(sim[B,C,Q], axis=Q) @ enc[B,Q,D] -> out[B,C,D]
// B=32, C=4096, Q=512, D=512. fp32 in/out; bf16 MFMA with deferred
// softmax normalization: out = (exp(sim) @ enc) * (1/rowsum).

constexpr int Bn = 32;
constexpr int Cn = 4096;
constexpr int Qn = 512;
constexpr int Dn = 512;
constexpr int BM = 64;          // C-rows per block
constexpr int CK = 64;          // K-chunk
constexpr int NCHUNK = Qn / CK; // 8

typedef __attribute__((ext_vector_type(8))) short short8;
typedef __attribute__((ext_vector_type(4))) float floatx4;

__device__ __forceinline__ ushort f2bf(float f) {
  union { float f; unsigned u; } v; v.f = f;
  unsigned r = v.u + 0x7FFFu + ((v.u >> 16) & 1u);   // RNE
  return (ushort)(r >> 16);
}

// enc [B][Q][D] f32 -> Et [B][D][Q] bf16 (so MFMA B-frags are 16B contiguous)
__global__ __launch_bounds__(256) void transpose_conv(const float* __restrict__ E,
                                                      ushort* __restrict__ Et) {
  __shared__ float tile[32][33];
  int b = blockIdx.z, q0 = blockIdx.y * 32, d0 = blockIdx.x * 32;
  int x = threadIdx.x & 31, y = threadIdx.x >> 5;
  const float* src = E + ((size_t)b * Qn + q0) * Dn + d0;
#pragma unroll
  for (int k = 0; k < 4; ++k)
    tile[y + 8 * k][x] = src[(size_t)(y + 8 * k) * Dn + x];
  __syncthreads();
  ushort* dst = Et + ((size_t)b * Dn + d0) * Qn + q0;
#pragma unroll
  for (int k = 0; k < 4; ++k)
    dst[(size_t)(y + 8 * k) * Qn + x] = f2bf(tile[x][y + 8 * k]);
}

// One block = one b, 64 C-rows, 8 waves; per-wave output tile 64x64.
// Pipelined over 8 K-chunks of 64 with double-buffered exp'd-bf16 LDS tile.
__global__ __launch_bounds__(512, 4) void c2q_fused(const float* __restrict__ sim,
                                                    const ushort* __restrict__ Et,
                                                    float* __restrict__ out) {
  __shared__ char Pbuf[2][BM * CK * 2];  // 2 x 8KB, XOR-swizzled
  __shared__ float rsInv[BM];

  const int tid  = threadIdx.x;
  const int lane = tid & 63;
  const int wid  = tid >> 6;           // 0..7 -> d-group
  const int l16  = lane & 15;
  const int lhi  = lane >> 4;          // 0..3

  // bijective XCD swizzle: each XCD gets 256 contiguous logical blocks
  // (= 4 consecutive b values -> Et working set 2MB fits 4MB XCD L2)
  const int orig = blockIdx.x;               // 2048 blocks, 2048%8==0
  const int cpx  = gridDim.x >> 3;
  const int logical = (orig & 7) * cpx + (orig >> 3);
  const int b  = logical >> 6;
  const int c0 = (logical & 63) * BM;

  const float* simb = sim + ((size_t)b * Cn + c0) * Qn;

  // staging role: thread owns row srow, k-slice [skp*8, skp*8+8) of each chunk
  const int srow = tid >> 3;   // 0..63
  const int skp  = tid & 7;    // 0..7
  const float* sload = simb + (size_t)srow * Qn + skp * 8;
  const int soff = (srow * 128 + skp * 16) ^ ((srow & 7) << 4);

  float rsum = 0.0f;

  // ---- prologue: stage chunk 0 ----
  {
    float4 v0 = *(const float4*)(sload);
    float4 v1 = *(const float4*)(sload + 4);
    float e0 = __expf(v0.x), e1 = __expf(v0.y), e2 = __expf(v0.z), e3 = __expf(v0.w);
    float e4 = __expf(v1.x), e5 = __expf(v1.y), e6 = __expf(v1.z), e7 = __expf(v1.w);
    rsum += ((e0 + e1) + (e2 + e3)) + ((e4 + e5) + (e6 + e7));
    uint4 pk;
    pk.x = (uint)f2bf(e0) | ((uint)f2bf(e1) << 16);
    pk.y = (uint)f2bf(e2) | ((uint)f2bf(e3) << 16);
    pk.z = (uint)f2bf(e4) | ((uint)f2bf(e5) << 16);
    pk.w = (uint)f2bf(e6) | ((uint)f2bf(e7) << 16);
    *(uint4*)(Pbuf[0] + soff) = pk;
  }
  __syncthreads();

  floatx4 acc[4][4] = {};
  const ushort* EtB = Et + ((size_t)b * Dn + wid * 64 + l16) * Qn + lhi * 8;

#pragma unroll 2
  for (int t = 0; t < NCHUNK; ++t) {
    // T14 split: issue next chunk's sim loads BEFORE the MFMA section
    float4 v0, v1;
    if (t < NCHUNK - 1) {
      v0 = *(const float4*)(sload + (t + 1) * CK);
      v1 = *(const float4*)(sload + (t + 1) * CK + 4);
    }

    // ---- MFMA on buf[t&1] ----
    const char* pb = Pbuf[t & 1];
#pragma unroll
    for (int kk = 0; kk < 2; ++kk) {
      short8 a[4], bb[4];
#pragma unroll
      for (int mr = 0; mr < 4; ++mr) {
        int row = mr * 16 + l16;
        int off = (row * 128 + kk * 64 + lhi * 16) ^ ((row & 7) << 4);
        a[mr] = *(const short8*)(pb + off);
      }
#pragma unroll
      for (int nr = 0; nr < 4; ++nr)
        bb[nr] = *(const short8*)(EtB + (size_t)nr * 16 * Qn + t * CK + kk * 32);
#pragma unroll
      for (int mr = 0; mr < 4; ++mr)
#pragma unroll
        for (int nr = 0; nr < 4; ++nr)
          acc[mr][nr] = __builtin_amdgcn_mfma_f32_16x16x32_bf16(a[mr], bb[nr],
                                                                acc[mr][nr], 0, 0, 0);
    }

    if (t < NCHUNK - 1) {
      // ---- finish staging chunk t+1 (exp after MFMA; loads were in flight) ----
      float e0 = __expf(v0.x), e1 = __expf(v0.y), e2 = __expf(v0.z), e3 = __expf(v0.w);
      float e4 = __expf(v1.x), e5 = __expf(v1.y), e6 = __expf(v1.z), e7 = __expf(v1.w);
      rsum += ((e0 + e1) + (e2 + e3)) + ((e4 + e5) + (e6 + e7));
      uint4 pk;
      pk.x = (uint)f2bf(e0) | ((uint)f2bf(e1) << 16);
      pk.y = (uint)f2bf(e2) | ((uint)f2bf(e3) << 16);
      pk.z = (uint)f2bf(e4) | ((uint)f2bf(e5) << 16);
      pk.w = (uint)f2bf(e6) | ((uint)f2bf(e7) << 16);
      *(uint4*)(Pbuf[(t + 1) & 1] + soff) = pk;
    } else {
      // ---- finalize rowsums: 8 threads per row are lanes skp=0..7 ----
      rsum += __shfl_xor(rsum, 1);
      rsum += __shfl_xor(rsum, 2);
      rsum += __shfl_xor(rsum, 4);
      if (skp == 0) rsInv[srow] = 1.0f / rsum;
    }
    __syncthreads();
  }

  // ---- epilogue: scale by 1/rowsum, store ----
  float* outp = out + ((size_t)b * Cn + c0) * Dn;
#pragma unroll
  for (int mr = 0; mr < 4; ++mr) {
    float rs[4];
#pragma unroll
    for (int rr = 0; rr < 4; ++rr) rs[rr] = rsInv[mr * 16 + lhi * 4 + rr];
#pragma unroll
    for (int nr = 0; nr < 4; ++nr) {
      int col = wid * 64 + nr * 16 + l16;
#pragma unroll
      for (int rr = 0; rr < 4; ++rr) {
        int row = mr * 16 + lhi * 4 + rr;
        outp[(size_t)row * Dn + col] = acc[mr][nr][rr] * rs[rr];
      }
    }
  }
}

extern "C" void kernel_launch(void* const* d_in, const int* in_sizes, int n_in,
                              void* d_out, int out_size, void* d_ws, size_t ws_size,
                              hipStream_t stream) {
  const float* sim = (const float*)d_in[0];
  const float* enc = (const float*)d_in[1];
  float* outp = (float*)d_out;
  ushort* Et = (ushort*)d_ws;  // 32*512*512*2 = 16.8 MB

  transpose_conv<<<dim3(Dn / 32, Qn / 32, Bn), 256, 0, stream>>>(enc, Et);
  c2q_fused<<<dim3((Cn / BM) * Bn), 512, 0, stream>>>(sim, Et, outp);
}

// Round 3
// 205.137 us; speedup vs baseline: 1.6321x; 1.6321x over previous
//
#include <hip/hip_runtime.h>
#include <hip/hip_bf16.h>

// C2QAttention: softmax(sim[B,C,Q], axis=Q) @ enc[B,Q,D] -> out[B,C,D]
// B=32, C=4096, Q=512, D=512. fp32 in/out; bf16 MFMA with deferred
// softmax normalization: out = (exp(sim) @ enc) * (1/rowsum).

constexpr int Bn = 32;
constexpr int Cn = 4096;
constexpr int Qn = 512;
constexpr int Dn = 512;
constexpr int BM = 64;   // C-rows per block

typedef __attribute__((ext_vector_type(8))) short short8;
typedef __attribute__((ext_vector_type(4))) float floatx4;

__device__ __forceinline__ ushort f2bf(float f) {
  union { float f; unsigned u; } v; v.f = f;
  unsigned r = v.u + 0x7FFFu + ((v.u >> 16) & 1u);   // RNE
  return (ushort)(r >> 16);
}

// enc [B][Q][D] f32 -> Et [B][D][Q] bf16 (so MFMA B-frags are 16B contiguous)
__global__ __launch_bounds__(256) void transpose_conv(const float* __restrict__ E,
                                                      ushort* __restrict__ Et) {
  __shared__ float tile[32][33];
  int b = blockIdx.z, q0 = blockIdx.y * 32, d0 = blockIdx.x * 32;
  int x = threadIdx.x & 31, y = threadIdx.x >> 5;
  const float* src = E + ((size_t)b * Qn + q0) * Dn + d0;
#pragma unroll
  for (int k = 0; k < 4; ++k)
    tile[y + 8 * k][x] = src[(size_t)(y + 8 * k) * Dn + x];
  __syncthreads();
  ushort* dst = Et + ((size_t)b * Dn + d0) * Qn + q0;
#pragma unroll
  for (int k = 0; k < 4; ++k)
    dst[(size_t)(y + 8 * k) * Qn + x] = f2bf(tile[x][y + 8 * k]);
}

// One block = one b, 64 C-rows, 8 waves.
// Phase A: deferred-norm exp staging, all 16 sim loads in flight per thread.
// Phase B: P[64,512] x Et^T via 16x16x32 bf16 MFMA, Et prefetch 1 k-step ahead.
__global__ __launch_bounds__(512, 4) void c2q_fused(const float* __restrict__ sim,
                                                    const ushort* __restrict__ Et,
                                                    float* __restrict__ out) {
  __shared__ char Plds[BM * Qn * 2];  // 64 KB bf16, XOR-swizzled rows
  __shared__ float rsInv[BM];

  const int tid  = threadIdx.x;
  const int lane = tid & 63;
  const int wid  = tid >> 6;           // 0..7 -> d-group
  const int l16  = lane & 15;
  const int lhi  = lane >> 4;          // 0..3
  const int b    = blockIdx.y;
  const int c0   = blockIdx.x * BM;

  // ---------------- Phase A: exp + stage (deferred normalization) ----------
  const int srow = tid >> 3;   // 0..63
  const int skp  = tid & 7;    // 0..7
  const float* sload = sim + ((size_t)b * Cn + c0 + srow) * Qn + skp * 8;

  float4 v[16];
#pragma unroll
  for (int c = 0; c < 8; ++c) {
    v[2 * c]     = *(const float4*)(sload + c * 64);
    v[2 * c + 1] = *(const float4*)(sload + c * 64 + 4);
  }
  float rsum = 0.0f;
#pragma unroll
  for (int c = 0; c < 8; ++c) {
    float e0 = __expf(v[2 * c].x),     e1 = __expf(v[2 * c].y);
    float e2 = __expf(v[2 * c].z),     e3 = __expf(v[2 * c].w);
    float e4 = __expf(v[2 * c + 1].x), e5 = __expf(v[2 * c + 1].y);
    float e6 = __expf(v[2 * c + 1].z), e7 = __expf(v[2 * c + 1].w);
    rsum += ((e0 + e1) + (e2 + e3)) + ((e4 + e5) + (e6 + e7));
    uint4 pk;
    pk.x = (uint)f2bf(e0) | ((uint)f2bf(e1) << 16);
    pk.y = (uint)f2bf(e2) | ((uint)f2bf(e3) << 16);
    pk.z = (uint)f2bf(e4) | ((uint)f2bf(e5) << 16);
    pk.w = (uint)f2bf(e6) | ((uint)f2bf(e7) << 16);
    int off = (srow << 10) + (c << 7) + (skp << 4);
    off ^= (srow & 7) << 4;            // bank-conflict swizzle
    *(uint4*)(Plds + off) = pk;
  }
  rsum += __shfl_xor(rsum, 1);
  rsum += __shfl_xor(rsum, 2);
  rsum += __shfl_xor(rsum, 4);
  if (skp == 0) rsInv[srow] = 1.0f / rsum;
  __syncthreads();

  // ---------------- Phase B: GEMM ----------------
  floatx4 acc[4][4] = {};
  const ushort* EtB = Et + ((size_t)b * Dn + wid * 64 + l16) * Qn + lhi * 8;

  short8 bb[4], nb[4];
#pragma unroll
  for (int nr = 0; nr < 4; ++nr)
    bb[nr] = *(const short8*)(EtB + (size_t)nr * 16 * Qn);

#pragma unroll
  for (int ks = 0; ks < 16; ++ks) {
    if (ks < 15) {
#pragma unroll
      for (int nr = 0; nr < 4; ++nr)
        nb[nr] = *(const short8*)(EtB + (size_t)nr * 16 * Qn + (ks + 1) * 32);
    }
    short8 a[4];
#pragma unroll
    for (int mr = 0; mr < 4; ++mr) {
      int row = mr * 16 + l16;
      int off = (row << 10) + (ks << 6) + (lhi << 4);
      off ^= (row & 7) << 4;
      a[mr] = *(const short8*)(Plds + off);
    }
    __builtin_amdgcn_s_setprio(1);
#pragma unroll
    for (int mr = 0; mr < 4; ++mr)
#pragma unroll
      for (int nr = 0; nr < 4; ++nr)
        acc[mr][nr] = __builtin_amdgcn_mfma_f32_16x16x32_bf16(a[mr], bb[nr],
                                                              acc[mr][nr], 0, 0, 0);
    __builtin_amdgcn_s_setprio(0);
#pragma unroll
    for (int nr = 0; nr < 4; ++nr) bb[nr] = nb[nr];
  }

  // ---------------- epilogue: scale by 1/rowsum, store ----------------
  float* outp = out + ((size_t)b * Cn + c0) * Dn;
#pragma unroll
  for (int mr = 0; mr < 4; ++mr) {
    float rs[4];
#pragma unroll
    for (int rr = 0; rr < 4; ++rr) rs[rr] = rsInv[mr * 16 + lhi * 4 + rr];
#pragma unroll
    for (int nr = 0; nr < 4; ++nr) {
      int col = wid * 64 + nr * 16 + l16;
#pragma unroll
      for (int rr = 0; rr < 4; ++rr) {
        int row = mr * 16 + lhi * 4 + rr;
        outp[(size_t)row * Dn + col] = acc[mr][nr][rr] * rs[rr];
      }
    }
  }
}

extern "C" void kernel_launch(void* const* d_in, const int* in_sizes, int n_in,
                              void* d_out, int out_size, void* d_ws, size_t ws_size,
                              hipStream_t stream) {
  const float* sim = (const float*)d_in[0];
  const float* enc = (const float*)d_in[1];
  float* outp = (float*)d_out;
  ushort* Et = (ushort*)d_ws;  // 32*512*512*2 = 16.8 MB

  transpose_conv<<<dim3(Dn / 32, Qn / 32, Bn), 256, 0, stream>>>(enc, Et);
  c2q_fused<<<dim3(Cn / BM, Bn), 512, 0, stream>>>(sim, Et, outp);
}